// Round 19
// baseline (222.837 us; speedup 1.0000x reference)
//
#include <hip/hip_runtime.h>
#include <math.h>

#define NN 100000
#define DIM 64
#define ENT_OFFSET 20000
#define BSH 7       // 128 rows per bucket
#define NBK 782     // ceil(100000/128)
#define TILE_C 8192 // edges per hist/scatter tile
#define MAXT 200    // max tiles (E=1.6M -> 196)
#define CAPD 4096   // flagged-only max ~1.5K/bucket
#define HPAD 68     // layer LDS row pad (halves)
#define SRP 168     // score LDS row pad (halves)

typedef _Float16 f16;
typedef _Float16 f16x2 __attribute__((ext_vector_type(2)));
typedef _Float16 f16x4 __attribute__((ext_vector_type(4)));
typedef _Float16 f16x8 __attribute__((ext_vector_type(8)));
typedef float f32x4 __attribute__((ext_vector_type(4)));

#if __has_builtin(__builtin_amdgcn_fdot2)
__device__ inline float FDOT2(f16x2 a, f16x2 b, float c) {
    return __builtin_amdgcn_fdot2(a, b, c, false);
}
#else
__device__ inline float FDOT2(f16x2 a, f16x2 b, float c) {
    return c + (float)a.x * (float)b.x + (float)a.y * (float)b.y;
}
#endif

// ---------------- Stage A: fusion -> e0c [N,64] f16 ----------------
__global__ void fuse_kernel(const float* __restrict__ aux,
                            const float* __restrict__ entity,
                            const float* __restrict__ type_emb,
                            const float* __restrict__ W_aux,
                            const float* __restrict__ b_aux,
                            f16* __restrict__ e0c)
{
    int n    = blockIdx.x * 4 + (threadIdx.x >> 6);
    int lane = threadIdx.x & 63;

    float la = 0.0f;
    if (lane < 3) la = __logf(1.0f + aux[n * 3 + lane]);
    float a0 = __shfl(la, 0);
    float a1 = __shfl(la, 1);
    float a2 = __shfl(la, 2);

    float g = fmaf(a0, W_aux[lane * 3 + 0],
              fmaf(a1, W_aux[lane * 3 + 1],
              fmaf(a2, W_aux[lane * 3 + 2], b_aux[lane])));
    float eneg = __expf(-g);
    g = __builtin_amdgcn_rcpf(1.0f + eneg) * 0.15f + 1.0f;

    float v  = entity[n * 64 + lane] * g;
    float ss = v * v;
    #pragma unroll
    for (int m = 32; m >= 1; m >>= 1) ss += __shfl_xor(ss, m);
    v = v * rsqrtf(fmaxf(ss, 1e-24f));
    v += type_emb[(n >= ENT_OFFSET ? 1 : 0) * 64 + lane];

    e0c[(size_t)n * 64 + lane] = (f16)v;
}

// ---------------- Demand-cone marking (COO scan) ----------------
__global__ void mark_ids(const int* __restrict__ uids, int nu,
                         const int* __restrict__ iids, int ni,
                         int* __restrict__ f0, int* __restrict__ f1)
{
    int i = blockIdx.x * blockDim.x + threadIdx.x;
    if (i >= nu + ni) return;
    int r = (i < nu) ? uids[i] : iids[i - nu];
    f1[r] = 1;
    f0[r] = 1;
}

__global__ void mark_edges(const int* __restrict__ rows, const int* __restrict__ cols,
                           int E, const int* __restrict__ f1, int* __restrict__ f0)
{
    int i = blockIdx.x * blockDim.x + threadIdx.x;
    int s = gridDim.x * blockDim.x;
    for (; i < E; i += s)
        if (f1[rows[i]]) f0[cols[i]] = 1;
}

__global__ __launch_bounds__(256) void compact_kernel(const int* __restrict__ flags,
                                                      int* __restrict__ list,
                                                      int* __restrict__ cnt)
{
    __shared__ int lds[256];
    __shared__ int base;
    int tid = threadIdx.x;
    int i = blockIdx.x * 256 + tid;
    int f = (i < NN) ? flags[i] : 0;
    lds[tid] = f;
    __syncthreads();
    for (int off = 1; off < 256; off <<= 1) {
        int v = (tid >= off) ? lds[tid - off] : 0;
        __syncthreads();
        lds[tid] += v;
        __syncthreads();
    }
    if (tid == 255) {
        int total = lds[255];
        base = total ? atomicAdd(cnt, total) : 0;
    }
    __syncthreads();
    if (f) list[base + lds[tid] - 1] = i;
}

// ---------------- hist: per-tile local counts + global counts + ebit ----------------
__global__ __launch_bounds__(1024) void bucket_hist(
    const int* __restrict__ rows, int E, const int* __restrict__ f0,
    int* __restrict__ bcnt, unsigned char* __restrict__ ebit,
    int* __restrict__ locCnt)                  // [tile][NBK]
{
    __shared__ int lh[NBK];
    int tid   = threadIdx.x;
    int gbase = blockIdx.x * TILE_C;
    int n     = min(TILE_C, E - gbase);

    for (int b = tid; b < NBK; b += 1024) lh[b] = 0;
    __syncthreads();
    for (int i = tid; i < n; i += 1024) {
        int r = rows[gbase + i];
        int keep = f0[r];
        ebit[gbase + i] = (unsigned char)keep;
        if (keep) atomicAdd(&lh[r >> BSH], 1);
    }
    __syncthreads();
    for (int b = tid; b < NBK; b += 1024) {
        int c = lh[b];
        locCnt[(size_t)blockIdx.x * NBK + b] = c;
        if (c) atomicAdd(&bcnt[b], c);
    }
}

__global__ __launch_bounds__(1024) void bucket_scan(const int* __restrict__ bcnt,
                                                    int* __restrict__ bstart,
                                                    int* __restrict__ rowptr)
{
    __shared__ int lds[1024];
    int t = threadIdx.x;
    int v = (t < NBK) ? bcnt[t] : 0;
    lds[t] = v;
    __syncthreads();
    for (int off = 1; off < 1024; off <<= 1) {
        int u = (t >= off) ? lds[t - off] : 0;
        __syncthreads();
        lds[t] += u;
        __syncthreads();
    }
    if (t < NBK) bstart[t + 1] = lds[t];
    if (t == 0)  bstart[0] = 0;
    if (t == NBK - 1) rowptr[NN] = lds[t];   // total flagged edges
}

// per-bucket exclusive scan over tiles -> exact write base per (tile,bucket)
__global__ __launch_bounds__(256) void gpos_scan(const int* __restrict__ bstart,
                                                 const int* __restrict__ locCnt,
                                                 int* __restrict__ gposM, int ntiles)
{
    int b = blockIdx.x * blockDim.x + threadIdx.x;
    if (b >= NBK) return;
    int run = bstart[b];
    for (int t = 0; t < ntiles; t++) {
        gposM[(size_t)t * NBK + b] = run;
        run += locCnt[(size_t)t * NBK + b];
    }
}

// SINGLE-PASS scatter: offsets precomputed; only local fill atomics remain.
__global__ __launch_bounds__(1024) void bucket_scatter(
    const int* __restrict__ rows, const int* __restrict__ cols,
    const float* __restrict__ vals, int E, const unsigned char* __restrict__ ebit,
    const int* __restrict__ gposM, uint2* __restrict__ cv)
{
    __shared__ int lfill[NBK];
    __shared__ int gbse[NBK];
    int tid   = threadIdx.x;
    int gbase = blockIdx.x * TILE_C;
    int n     = min(TILE_C, E - gbase);

    for (int b = tid; b < NBK; b += 1024) {
        lfill[b] = 0;
        gbse[b]  = gposM[(size_t)blockIdx.x * NBK + b];
    }
    __syncthreads();
    for (int i = tid; i < n; i += 1024) {
        if (!ebit[gbase + i]) continue;
        int r = rows[gbase + i];
        int b = r >> BSH;
        int ofs = atomicAdd(&lfill[b], 1);
        unsigned meta = (unsigned)cols[gbase + i] | ((unsigned)(r & 127) << 17);
        cv[gbse[b] + ofs] = make_uint2(meta, __float_as_uint(vals[gbase + i]));
    }
}

__global__ __launch_bounds__(256) void bucket_sort(
    const int* __restrict__ bstart, uint2* __restrict__ cv, int* __restrict__ rowptr)
{
    __shared__ uint2 raw[CAPD];
    __shared__ int hist[128], excl[128], fill[128];
    int b = blockIdx.x, tid = threadIdx.x;
    int base = bstart[b];
    int count = bstart[b + 1] - base;

    if (tid < 128) { hist[tid] = 0; fill[tid] = 0; }
    __syncthreads();
    for (int i = tid; i < count && i < CAPD; i += 256) {
        uint2 e = cv[base + i];
        raw[i] = e;
        atomicAdd(&hist[(e.x >> 17) & 127], 1);
    }
    __syncthreads();
    if (tid < 128) excl[tid] = hist[tid];
    __syncthreads();
    for (int off = 1; off < 128; off <<= 1) {
        int v = (tid < 128 && tid >= off) ? excl[tid - off] : 0;
        __syncthreads();
        if (tid < 128) excl[tid] += v;
        __syncthreads();
    }
    if (tid < 128) {
        int ex = excl[tid] - hist[tid];
        excl[tid] = ex;
        int g = (b << BSH) + tid;
        if (g < NN) rowptr[g] = base + ex;
    }
    __syncthreads();
    for (int i = tid; i < count && i < CAPD; i += 256) {
        uint2 e = raw[i];
        int lr = (e.x >> 17) & 127;
        int ofs = excl[lr] + atomicAdd(&fill[lr], 1);
        cv[base + ofs] = make_uint2(e.x & 0x1FFFF, e.y);
    }
}

// ---------------- SpMM (CSR, listed rows): one wave per row, 16-deep gathers ----------------
template <int STR>
__global__ __launch_bounds__(256) void spmm_csr_list(
    const int* __restrict__ rowptr, const uint2* __restrict__ cv,
    const f16* __restrict__ x, f16* __restrict__ side,
    const int* __restrict__ list, const int* __restrict__ cnt)
{
    int wid = (blockIdx.x * blockDim.x + threadIdx.x) >> 6;
    if (wid >= *cnt) return;
    int r = list[wid];
    int lane = threadIdx.x & 63;
    int s = rowptr[r], e = rowptr[r + 1];

    float acc = 0.0f;
    int i = s;
    for (; i + 16 <= e; i += 16) {
        uint2 ce[16];
        float xv[16];
        #pragma unroll
        for (int k = 0; k < 16; k++) ce[k] = cv[i + k];
        #pragma unroll
        for (int k = 0; k < 16; k++)
            xv[k] = (float)x[(size_t)ce[k].x * STR + lane];
        #pragma unroll
        for (int k = 0; k < 16; k++)
            acc = fmaf(__uint_as_float(ce[k].y), xv[k], acc);
    }
    for (; i + 4 <= e; i += 4) {
        uint2 e0 = cv[i], e1 = cv[i + 1], e2 = cv[i + 2], e3 = cv[i + 3];
        float x0 = (float)x[(size_t)e0.x * STR + lane];
        float x1 = (float)x[(size_t)e1.x * STR + lane];
        float x2 = (float)x[(size_t)e2.x * STR + lane];
        float x3 = (float)x[(size_t)e3.x * STR + lane];
        acc += __uint_as_float(e0.y) * x0 + __uint_as_float(e1.y) * x1
             + __uint_as_float(e2.y) * x2 + __uint_as_float(e3.y) * x3;
    }
    for (; i < e; i++) {
        uint2 e0 = cv[i];
        acc += __uint_as_float(e0.y) * (float)x[(size_t)e0.x * STR + lane];
    }
    side[r * 64 + lane] = (f16)acc;
}

// ---------------- Dense conv layer over listed rows ----------------
template <int OUT, int XSTR, int OSTR, bool WRITE_RAW>
__global__ __launch_bounds__(256) void layer_kernel(
    const f16* __restrict__ x,
    const f16* __restrict__ side,
    const float* __restrict__ W1, const float* __restrict__ b1,
    const float* __restrict__ W2, const float* __restrict__ b2,
    f16* __restrict__ out_norm,
    f16* __restrict__ out_raw,
    const int* __restrict__ list, const int* __restrict__ cnt)
{
    constexpr int OPT = OUT / 8;
    __shared__ f16 W1h[OUT * HPAD];
    __shared__ f16 W2h[OUT * HPAD];
    __shared__ f16 s_sum[64 * HPAD];
    __shared__ f16 s_bi [64 * HPAD];

    int tid  = threadIdx.x;
    int n0   = blockIdx.x * 64;
    int cntv = *cnt;
    if (n0 >= cntv) return;

    for (int t = tid; t < OUT * 64; t += 256) {
        int r = t >> 6, c = t & 63;
        W1h[r * HPAD + c] = (f16)W1[t];
        W2h[r * HPAD + c] = (f16)W2[t];
    }
    for (int t = tid; t < 64 * 16; t += 256) {
        int n = t >> 4, q = t & 15;
        int li = n0 + n;
        f16x4 xe = {0,0,0,0}, sd = {0,0,0,0};
        if (li < cntv) {
            int gn = list[li];
            xe = *(const f16x4*)&x[(size_t)gn * XSTR + q * 4];
            sd = *(const f16x4*)&side[(size_t)gn * 64 + q * 4];
        }
        f16x4 sm, bi;
        #pragma unroll
        for (int k = 0; k < 4; k++) {
            float xf = (float)xe[k], sf = (float)sd[k];
            sm[k] = (f16)(xf + sf);
            bi[k] = (f16)(xf * sf);
        }
        *(f16x4*)&s_sum[n * HPAD + q * 4] = sm;
        *(f16x4*)&s_bi [n * HPAD + q * 4] = bi;
    }
    __syncthreads();

    int og = tid & 7;
    int nb = tid >> 3;
    int nA = nb * 2, nB = nA + 1;

    float acc1[2][OPT], acc2[2][OPT];
    #pragma unroll
    for (int i = 0; i < OPT; i++) {
        int o = og + 8 * i;
        acc1[0][i] = b1[o]; acc1[1][i] = b1[o];
        acc2[0][i] = b2[o]; acc2[1][i] = b2[o];
    }

    #pragma unroll 4
    for (int d4 = 0; d4 < 16; d4++) {
        f16x4 sA = *(const f16x4*)&s_sum[nA * HPAD + d4 * 4];
        f16x4 bA = *(const f16x4*)&s_bi [nA * HPAD + d4 * 4];
        f16x4 sB = *(const f16x4*)&s_sum[nB * HPAD + d4 * 4];
        f16x4 bB = *(const f16x4*)&s_bi [nB * HPAD + d4 * 4];
        f16x2 sA0 = {sA[0], sA[1]}, sA1 = {sA[2], sA[3]};
        f16x2 bA0 = {bA[0], bA[1]}, bA1 = {bA[2], bA[3]};
        f16x2 sB0 = {sB[0], sB[1]}, sB1 = {sB[2], sB[3]};
        f16x2 bB0 = {bB[0], bB[1]}, bB1 = {bB[2], bB[3]};
        #pragma unroll
        for (int i = 0; i < OPT; i++) {
            int o = og + 8 * i;
            f16x4 w1 = *(const f16x4*)&W1h[o * HPAD + d4 * 4];
            f16x4 w2 = *(const f16x4*)&W2h[o * HPAD + d4 * 4];
            f16x2 w10 = {w1[0], w1[1]}, w11 = {w1[2], w1[3]};
            f16x2 w20 = {w2[0], w2[1]}, w21 = {w2[2], w2[3]};
            acc1[0][i] = FDOT2(sA1, w11, FDOT2(sA0, w10, acc1[0][i]));
            acc1[1][i] = FDOT2(sB1, w11, FDOT2(sB0, w10, acc1[1][i]));
            acc2[0][i] = FDOT2(bA1, w21, FDOT2(bA0, w20, acc2[0][i]));
            acc2[1][i] = FDOT2(bB1, w21, FDOT2(bB0, w20, acc2[1][i]));
        }
    }

    float eo[2][OPT];
    float ss0 = 0.0f, ss1 = 0.0f;
    #pragma unroll
    for (int i = 0; i < OPT; i++) {
        float a = acc1[0][i]; a = a > 0.0f ? a : 0.01f * a;
        float c = acc2[0][i]; c = c > 0.0f ? c : 0.01f * c;
        eo[0][i] = a + c; ss0 += eo[0][i] * eo[0][i];
        a = acc1[1][i]; a = a > 0.0f ? a : 0.01f * a;
        c = acc2[1][i]; c = c > 0.0f ? c : 0.01f * c;
        eo[1][i] = a + c; ss1 += eo[1][i] * eo[1][i];
    }
    #pragma unroll
    for (int m = 1; m <= 4; m <<= 1) {
        ss0 += __shfl_xor(ss0, m);
        ss1 += __shfl_xor(ss1, m);
    }
    float inv0 = rsqrtf(fmaxf(ss0, 1e-24f));
    float inv1 = rsqrtf(fmaxf(ss1, 1e-24f));

    int liA = n0 + nA, liB = n0 + nB;
    int gnA = (liA < cntv) ? list[liA] : -1;
    int gnB = (liB < cntv) ? list[liB] : -1;
    #pragma unroll
    for (int i = 0; i < OPT; i++) {
        int o = og + 8 * i;
        if (gnA >= 0) {
            out_norm[(size_t)gnA * OSTR + o] = (f16)(eo[0][i] * inv0);
            if (WRITE_RAW) out_raw[(size_t)gnA * 64 + o] = (f16)eo[0][i];
        }
        if (gnB >= 0) {
            out_norm[(size_t)gnB * OSTR + o] = (f16)(eo[1][i] * inv1);
            if (WRITE_RAW) out_raw[(size_t)gnB * 64 + o] = (f16)eo[1][i];
        }
    }
}

// ---------------- Score GEMM: MFMA 16x16x32 f16, rows from e0c(64) + e12(96) ----------------
__global__ __launch_bounds__(256) void score_kernel(
    const f16* __restrict__ e0c, const f16* __restrict__ e12,
    const int* __restrict__ uids, const int* __restrict__ iids,
    float* __restrict__ out, int n_items)
{
    __shared__ f16 Us[64 * SRP];
    __shared__ f16 Vs[64 * SRP];
    int tid = threadIdx.x;
    int i0 = blockIdx.y * 64, j0 = blockIdx.x * 64;

    for (int t = tid; t < 64 * 20; t += 256) {
        int r = t / 20, c = t % 20;
        int uid = uids[i0 + r];
        int iid = iids[j0 + r];
        f16x8 u, v;
        if (c < 8) {
            u = *(const f16x8*)&e0c[(size_t)uid * 64 + c * 8];
            v = *(const f16x8*)&e0c[(size_t)iid * 64 + c * 8];
        } else {
            u = *(const f16x8*)&e12[(size_t)uid * 96 + (c - 8) * 8];
            v = *(const f16x8*)&e12[(size_t)iid * 96 + (c - 8) * 8];
        }
        *(f16x8*)&Us[r * SRP + c * 8] = u;
        *(f16x8*)&Vs[r * SRP + c * 8] = v;
    }
    __syncthreads();

    int w = tid >> 6, lane = tid & 63;
    int wr = (w >> 1) * 32, wc = (w & 1) * 32;
    int lr = lane & 15, lk = (lane >> 4) * 8;

    f32x4 acc00 = {0,0,0,0}, acc01 = {0,0,0,0}, acc10 = {0,0,0,0}, acc11 = {0,0,0,0};
    #pragma unroll
    for (int kc = 0; kc < 160; kc += 32) {
        f16x8 a0 = *(const f16x8*)&Us[(wr +      lr) * SRP + kc + lk];
        f16x8 a1 = *(const f16x8*)&Us[(wr + 16 + lr) * SRP + kc + lk];
        f16x8 b0 = *(const f16x8*)&Vs[(wc +      lr) * SRP + kc + lk];
        f16x8 b1 = *(const f16x8*)&Vs[(wc + 16 + lr) * SRP + kc + lk];
        acc00 = __builtin_amdgcn_mfma_f32_16x16x32_f16(a0, b0, acc00, 0, 0, 0);
        acc01 = __builtin_amdgcn_mfma_f32_16x16x32_f16(a0, b1, acc01, 0, 0, 0);
        acc10 = __builtin_amdgcn_mfma_f32_16x16x32_f16(a1, b0, acc10, 0, 0, 0);
        acc11 = __builtin_amdgcn_mfma_f32_16x16x32_f16(a1, b1, acc11, 0, 0, 0);
    }

    int orow = (lane >> 4) * 4, ocol = lane & 15;
    #pragma unroll
    for (int r = 0; r < 4; r++) {
        int iA = i0 + wr + orow + r;
        int iB = i0 + wr + 16 + orow + r;
        out[(size_t)iA * n_items + j0 + wc +      ocol] = acc00[r];
        out[(size_t)iA * n_items + j0 + wc + 16 + ocol] = acc01[r];
        out[(size_t)iB * n_items + j0 + wc +      ocol] = acc10[r];
        out[(size_t)iB * n_items + j0 + wc + 16 + ocol] = acc11[r];
    }
}

extern "C" void kernel_launch(void* const* d_in, const int* in_sizes, int n_in,
                              void* d_out, int out_size, void* d_ws, size_t ws_size,
                              hipStream_t stream) {
    const int*   user_ids = (const int*)  d_in[0];
    const int*   item_ids = (const int*)  d_in[1];
    const float* aux      = (const float*)d_in[2];
    const int*   A_rows   = (const int*)  d_in[3];
    const int*   A_cols   = (const int*)  d_in[4];
    const float* A_vals   = (const float*)d_in[5];
    const float* entity   = (const float*)d_in[6];
    const float* type_emb = (const float*)d_in[7];
    const float* W_aux    = (const float*)d_in[8];
    const float* b_aux    = (const float*)d_in[9];
    const float* W1_0     = (const float*)d_in[10];
    const float* b1_0     = (const float*)d_in[11];
    const float* W2_0     = (const float*)d_in[12];
    const float* b2_0     = (const float*)d_in[13];
    const float* W1_1     = (const float*)d_in[14];
    const float* b1_1     = (const float*)d_in[15];
    const float* W2_1     = (const float*)d_in[16];
    const float* b2_1     = (const float*)d_in[17];

    int E       = in_sizes[3];
    int n_users = in_sizes[0];
    int n_items = in_sizes[1];
    int ntiles  = (E + TILE_C - 1) / TILE_C;

    char* ws = (char*)d_ws;
    size_t off = 0;
    f16*   e0c    = (f16*)  (ws + off); off += (size_t)NN * 64 * 2;    // 12.8 MB
    f16*   e12    = (f16*)  (ws + off); off += (size_t)NN * 96 * 2;    // 19.2 MB
    f16*   e1raw  = (f16*)  (ws + off); off += (size_t)NN * 64 * 2;    // 12.8 MB
    f16*   side   = (f16*)  (ws + off); off += (size_t)NN * 64 * 2;    // 12.8 MB
    uint2* cv     = (uint2*)(ws + off); off += (size_t)E * 8;          // 12.8 MB
    unsigned char* ebit = (unsigned char*)(ws + off); off += (size_t)E; // 1.6 MB
    int*   locCnt = (int*)  (ws + off); off += (size_t)MAXT * NBK * 4; // 0.63 MB
    int*   gposM  = (int*)  (ws + off); off += (size_t)MAXT * NBK * 4; // 0.63 MB
    int*   rowptr = (int*)  (ws + off); off += (size_t)(NN + 1) * 4;
    int*   bstart = (int*)  (ws + off); off += (size_t)(NBK + 1) * 4;
    int*   L0     = (int*)  (ws + off); off += (size_t)NN * 4;
    int*   L1     = (int*)  (ws + off); off += (size_t)NN * 4;
    // contiguous zero-init region: bcnt | f0 | f1 | cnt0 | cnt1
    char*  zbase  = ws + off;
    int*   bcnt   = (int*)  (ws + off); off += (size_t)NBK * 4;
    int*   f0     = (int*)  (ws + off); off += (size_t)NN * 4;
    int*   f1     = (int*)  (ws + off); off += (size_t)NN * 4;
    int*   cnt0   = (int*)  (ws + off); off += 4;
    int*   cnt1   = (int*)  (ws + off); off += 4;
    size_t zbytes = (size_t)(NBK + 2 * NN + 2) * 4;

    hipMemsetAsync(zbase, 0, zbytes, stream);

    // ---- Demand cone (COO scan): L1 = ids, L0 = L1 ∪ cols(rows in L1) ----
    int nid = n_users + n_items;
    mark_ids<<<(nid + 255) / 256, 256, 0, stream>>>(user_ids, n_users,
                                                    item_ids, n_items, f0, f1);
    mark_edges<<<2048, 256, 0, stream>>>(A_rows, A_cols, E, f1, f0);
    compact_kernel<<<(NN + 255) / 256, 256, 0, stream>>>(f0, L0, cnt0);
    compact_kernel<<<(NN + 255) / 256, 256, 0, stream>>>(f1, L1, cnt1);

    // ---- CSR build over flagged rows only (single-pass scatter) ----
    bucket_hist<<<ntiles, 1024, 0, stream>>>(A_rows, E, f0, bcnt, ebit, locCnt);
    bucket_scan<<<1, 1024, 0, stream>>>(bcnt, bstart, rowptr);
    gpos_scan<<<(NBK + 255) / 256, 256, 0, stream>>>(bstart, locCnt, gposM, ntiles);
    bucket_scatter<<<ntiles, 1024, 0, stream>>>(A_rows, A_cols, A_vals, E, ebit,
                                                gposM, cv);
    bucket_sort<<<NBK, 256, 0, stream>>>(bstart, cv, rowptr);

    // ---- Stage A: e0c (all nodes) ----
    fuse_kernel<<<NN / 4, 256, 0, stream>>>(aux, entity, type_emb, W_aux, b_aux, e0c);

    int sgrid_rows = (NN + 3) / 4;
    int lgrid      = (NN + 63) / 64;

    // ---- Layer 0 over L0: norm -> e12[:,0:64], raw -> e1raw ----
    spmm_csr_list<64><<<sgrid_rows, 256, 0, stream>>>(rowptr, cv, e0c, side, L0, cnt0);
    layer_kernel<64, 64, 96, true><<<lgrid, 256, 0, stream>>>(e0c, side,
                                                              W1_0, b1_0, W2_0, b2_0,
                                                              e12, e1raw, L0, cnt0);

    // ---- Layer 1 over L1: norm -> e12[:,64:96] ----
    spmm_csr_list<64><<<sgrid_rows, 256, 0, stream>>>(rowptr, cv, e1raw, side, L1, cnt1);
    layer_kernel<32, 64, 96, false><<<lgrid, 256, 0, stream>>>(e1raw, side,
                                                               W1_1, b1_1, W2_1, b2_1,
                                                               e12 + 64, nullptr, L1, cnt1);

    // ---- Score (MFMA) ----
    dim3 sgrid(n_items / 64, n_users / 64);
    score_kernel<<<sgrid, 256, 0, stream>>>(e0c, e12, user_ids, item_ids,
                                            (float*)d_out, n_items);
}

// Round 20
// 181.715 us; speedup vs baseline: 1.2263x; 1.2263x over previous
//
#include <hip/hip_runtime.h>
#include <math.h>

#define NN 100000
#define DIM 64
#define ENT_OFFSET 20000
#define BSH 7       // 128 rows per bucket
#define NBK 782     // ceil(100000/128)
#define TILE_C 8192 // edges per hist/scatter tile
#define MAXT 200    // max tiles (E=1.6M -> 196)
#define CAPD 4096   // flagged-only max ~1.5K/bucket
#define HPAD 68     // layer LDS row pad (halves)
#define SRP 168     // score LDS row pad (halves)

typedef _Float16 f16;
typedef _Float16 f16x2 __attribute__((ext_vector_type(2)));
typedef _Float16 f16x4 __attribute__((ext_vector_type(4)));
typedef _Float16 f16x8 __attribute__((ext_vector_type(8)));
typedef float f32x4 __attribute__((ext_vector_type(4)));

#if __has_builtin(__builtin_amdgcn_fdot2)
__device__ inline float FDOT2(f16x2 a, f16x2 b, float c) {
    return __builtin_amdgcn_fdot2(a, b, c, false);
}
#else
__device__ inline float FDOT2(f16x2 a, f16x2 b, float c) {
    return c + (float)a.x * (float)b.x + (float)a.y * (float)b.y;
}
#endif

// ---------------- Stage A: fusion -> e0c [N,64] f16 ----------------
__global__ void fuse_kernel(const float* __restrict__ aux,
                            const float* __restrict__ entity,
                            const float* __restrict__ type_emb,
                            const float* __restrict__ W_aux,
                            const float* __restrict__ b_aux,
                            f16* __restrict__ e0c)
{
    int n    = blockIdx.x * 4 + (threadIdx.x >> 6);
    int lane = threadIdx.x & 63;

    float la = 0.0f;
    if (lane < 3) la = __logf(1.0f + aux[n * 3 + lane]);
    float a0 = __shfl(la, 0);
    float a1 = __shfl(la, 1);
    float a2 = __shfl(la, 2);

    float g = fmaf(a0, W_aux[lane * 3 + 0],
              fmaf(a1, W_aux[lane * 3 + 1],
              fmaf(a2, W_aux[lane * 3 + 2], b_aux[lane])));
    float eneg = __expf(-g);
    g = __builtin_amdgcn_rcpf(1.0f + eneg) * 0.15f + 1.0f;

    float v  = entity[n * 64 + lane] * g;
    float ss = v * v;
    #pragma unroll
    for (int m = 32; m >= 1; m >>= 1) ss += __shfl_xor(ss, m);
    v = v * rsqrtf(fmaxf(ss, 1e-24f));
    v += type_emb[(n >= ENT_OFFSET ? 1 : 0) * 64 + lane];

    e0c[(size_t)n * 64 + lane] = (f16)v;
}

// ---------------- Demand-cone marking (COO scan) ----------------
__global__ void mark_ids(const int* __restrict__ uids, int nu,
                         const int* __restrict__ iids, int ni,
                         int* __restrict__ f0, int* __restrict__ f1)
{
    int i = blockIdx.x * blockDim.x + threadIdx.x;
    if (i >= nu + ni) return;
    int r = (i < nu) ? uids[i] : iids[i - nu];
    f1[r] = 1;
    f0[r] = 1;
}

__global__ void mark_edges(const int* __restrict__ rows, const int* __restrict__ cols,
                           int E, const int* __restrict__ f1, int* __restrict__ f0)
{
    int i = blockIdx.x * blockDim.x + threadIdx.x;
    int s = gridDim.x * blockDim.x;
    for (; i < E; i += s)
        if (f1[rows[i]]) f0[cols[i]] = 1;
}

__global__ __launch_bounds__(256) void compact_kernel(const int* __restrict__ flags,
                                                      int* __restrict__ list,
                                                      int* __restrict__ cnt)
{
    __shared__ int lds[256];
    __shared__ int base;
    int tid = threadIdx.x;
    int i = blockIdx.x * 256 + tid;
    int f = (i < NN) ? flags[i] : 0;
    lds[tid] = f;
    __syncthreads();
    for (int off = 1; off < 256; off <<= 1) {
        int v = (tid >= off) ? lds[tid - off] : 0;
        __syncthreads();
        lds[tid] += v;
        __syncthreads();
    }
    if (tid == 255) {
        int total = lds[255];
        base = total ? atomicAdd(cnt, total) : 0;
    }
    __syncthreads();
    if (f) list[base + lds[tid] - 1] = i;
}

// ---------------- hist: per-tile local counts (transposed) + global counts + ebit ----------------
__global__ __launch_bounds__(1024) void bucket_hist(
    const int* __restrict__ rows, int E, const int* __restrict__ f0,
    int* __restrict__ bcnt, unsigned char* __restrict__ ebit,
    int* __restrict__ locCnt)                  // [bucket][MAXT]
{
    __shared__ int lh[NBK];
    int tid   = threadIdx.x;
    int gbase = blockIdx.x * TILE_C;
    int n     = min(TILE_C, E - gbase);

    for (int b = tid; b < NBK; b += 1024) lh[b] = 0;
    __syncthreads();
    for (int i = tid; i < n; i += 1024) {
        int r = rows[gbase + i];
        int keep = f0[r];
        ebit[gbase + i] = (unsigned char)keep;
        if (keep) atomicAdd(&lh[r >> BSH], 1);
    }
    __syncthreads();
    for (int b = tid; b < NBK; b += 1024) {
        int c = lh[b];
        locCnt[(size_t)b * MAXT + blockIdx.x] = c;
        if (c) atomicAdd(&bcnt[b], c);
    }
}

__global__ __launch_bounds__(1024) void bucket_scan(const int* __restrict__ bcnt,
                                                    int* __restrict__ bstart,
                                                    int* __restrict__ rowptr)
{
    __shared__ int lds[1024];
    int t = threadIdx.x;
    int v = (t < NBK) ? bcnt[t] : 0;
    lds[t] = v;
    __syncthreads();
    for (int off = 1; off < 1024; off <<= 1) {
        int u = (t >= off) ? lds[t - off] : 0;
        __syncthreads();
        lds[t] += u;
        __syncthreads();
    }
    if (t < NBK) bstart[t + 1] = lds[t];
    if (t == 0)  bstart[0] = 0;
    if (t == NBK - 1) rowptr[NN] = lds[t];   // total flagged edges
}

// wave-parallel per-bucket scan over tiles: one 64-lane wave per bucket.
__global__ __launch_bounds__(256) void gpos_scan(const int* __restrict__ bstart,
                                                 const int* __restrict__ locCnt,
                                                 int* __restrict__ gposM, int ntiles)
{
    int b    = blockIdx.x * 4 + (threadIdx.x >> 6);
    int lane = threadIdx.x & 63;
    if (b >= NBK) return;

    int run = bstart[b];
    for (int c0 = 0; c0 < ntiles; c0 += 64) {
        int t = c0 + lane;
        int v = (t < ntiles) ? locCnt[(size_t)b * MAXT + t] : 0;
        int orig = v;
        #pragma unroll
        for (int off = 1; off < 64; off <<= 1) {
            int u = __shfl_up(v, off);
            if (lane >= off) v += u;
        }
        if (t < ntiles) gposM[(size_t)b * MAXT + t] = run + v - orig;
        run += __shfl(v, 63);
    }
}

// SINGLE-PASS scatter: offsets precomputed; only local fill atomics remain.
__global__ __launch_bounds__(1024) void bucket_scatter(
    const int* __restrict__ rows, const int* __restrict__ cols,
    const float* __restrict__ vals, int E, const unsigned char* __restrict__ ebit,
    const int* __restrict__ gposM, uint2* __restrict__ cv)
{
    __shared__ int lfill[NBK];
    __shared__ int gbse[NBK];
    int tid   = threadIdx.x;
    int gbase = blockIdx.x * TILE_C;
    int n     = min(TILE_C, E - gbase);

    for (int b = tid; b < NBK; b += 1024) {
        lfill[b] = 0;
        gbse[b]  = gposM[(size_t)b * MAXT + blockIdx.x];
    }
    __syncthreads();
    for (int i = tid; i < n; i += 1024) {
        if (!ebit[gbase + i]) continue;
        int r = rows[gbase + i];
        int b = r >> BSH;
        int ofs = atomicAdd(&lfill[b], 1);
        unsigned meta = (unsigned)cols[gbase + i] | ((unsigned)(r & 127) << 17);
        cv[gbse[b] + ofs] = make_uint2(meta, __float_as_uint(vals[gbase + i]));
    }
}

__global__ __launch_bounds__(256) void bucket_sort(
    const int* __restrict__ bstart, uint2* __restrict__ cv, int* __restrict__ rowptr)
{
    __shared__ uint2 raw[CAPD];
    __shared__ int hist[128], excl[128], fill[128];
    int b = blockIdx.x, tid = threadIdx.x;
    int base = bstart[b];
    int count = bstart[b + 1] - base;

    if (tid < 128) { hist[tid] = 0; fill[tid] = 0; }
    __syncthreads();
    for (int i = tid; i < count && i < CAPD; i += 256) {
        uint2 e = cv[base + i];
        raw[i] = e;
        atomicAdd(&hist[(e.x >> 17) & 127], 1);
    }
    __syncthreads();
    if (tid < 128) excl[tid] = hist[tid];
    __syncthreads();
    for (int off = 1; off < 128; off <<= 1) {
        int v = (tid < 128 && tid >= off) ? excl[tid - off] : 0;
        __syncthreads();
        if (tid < 128) excl[tid] += v;
        __syncthreads();
    }
    if (tid < 128) {
        int ex = excl[tid] - hist[tid];
        excl[tid] = ex;
        int g = (b << BSH) + tid;
        if (g < NN) rowptr[g] = base + ex;
    }
    __syncthreads();
    for (int i = tid; i < count && i < CAPD; i += 256) {
        uint2 e = raw[i];
        int lr = (e.x >> 17) & 127;
        int ofs = excl[lr] + atomicAdd(&fill[lr], 1);
        cv[base + ofs] = make_uint2(e.x & 0x1FFFF, e.y);
    }
}

// ---------------- SpMM (CSR, listed rows): one wave per row, 16-deep gathers ----------------
template <int STR>
__global__ __launch_bounds__(256) void spmm_csr_list(
    const int* __restrict__ rowptr, const uint2* __restrict__ cv,
    const f16* __restrict__ x, f16* __restrict__ side,
    const int* __restrict__ list, const int* __restrict__ cnt)
{
    int wid = (blockIdx.x * blockDim.x + threadIdx.x) >> 6;
    if (wid >= *cnt) return;
    int r = list[wid];
    int lane = threadIdx.x & 63;
    int s = rowptr[r], e = rowptr[r + 1];

    float acc = 0.0f;
    int i = s;
    for (; i + 16 <= e; i += 16) {
        uint2 ce[16];
        float xv[16];
        #pragma unroll
        for (int k = 0; k < 16; k++) ce[k] = cv[i + k];
        #pragma unroll
        for (int k = 0; k < 16; k++)
            xv[k] = (float)x[(size_t)ce[k].x * STR + lane];
        #pragma unroll
        for (int k = 0; k < 16; k++)
            acc = fmaf(__uint_as_float(ce[k].y), xv[k], acc);
    }
    for (; i + 4 <= e; i += 4) {
        uint2 e0 = cv[i], e1 = cv[i + 1], e2 = cv[i + 2], e3 = cv[i + 3];
        float x0 = (float)x[(size_t)e0.x * STR + lane];
        float x1 = (float)x[(size_t)e1.x * STR + lane];
        float x2 = (float)x[(size_t)e2.x * STR + lane];
        float x3 = (float)x[(size_t)e3.x * STR + lane];
        acc += __uint_as_float(e0.y) * x0 + __uint_as_float(e1.y) * x1
             + __uint_as_float(e2.y) * x2 + __uint_as_float(e3.y) * x3;
    }
    for (; i < e; i++) {
        uint2 e0 = cv[i];
        acc += __uint_as_float(e0.y) * (float)x[(size_t)e0.x * STR + lane];
    }
    side[r * 64 + lane] = (f16)acc;
}

// ---------------- Dense conv layer over listed rows ----------------
template <int OUT, int XSTR, int OSTR, bool WRITE_RAW>
__global__ __launch_bounds__(256) void layer_kernel(
    const f16* __restrict__ x,
    const f16* __restrict__ side,
    const float* __restrict__ W1, const float* __restrict__ b1,
    const float* __restrict__ W2, const float* __restrict__ b2,
    f16* __restrict__ out_norm,
    f16* __restrict__ out_raw,
    const int* __restrict__ list, const int* __restrict__ cnt)
{
    constexpr int OPT = OUT / 8;
    __shared__ f16 W1h[OUT * HPAD];
    __shared__ f16 W2h[OUT * HPAD];
    __shared__ f16 s_sum[64 * HPAD];
    __shared__ f16 s_bi [64 * HPAD];

    int tid  = threadIdx.x;
    int n0   = blockIdx.x * 64;
    int cntv = *cnt;
    if (n0 >= cntv) return;

    for (int t = tid; t < OUT * 64; t += 256) {
        int r = t >> 6, c = t & 63;
        W1h[r * HPAD + c] = (f16)W1[t];
        W2h[r * HPAD + c] = (f16)W2[t];
    }
    for (int t = tid; t < 64 * 16; t += 256) {
        int n = t >> 4, q = t & 15;
        int li = n0 + n;
        f16x4 xe = {0,0,0,0}, sd = {0,0,0,0};
        if (li < cntv) {
            int gn = list[li];
            xe = *(const f16x4*)&x[(size_t)gn * XSTR + q * 4];
            sd = *(const f16x4*)&side[(size_t)gn * 64 + q * 4];
        }
        f16x4 sm, bi;
        #pragma unroll
        for (int k = 0; k < 4; k++) {
            float xf = (float)xe[k], sf = (float)sd[k];
            sm[k] = (f16)(xf + sf);
            bi[k] = (f16)(xf * sf);
        }
        *(f16x4*)&s_sum[n * HPAD + q * 4] = sm;
        *(f16x4*)&s_bi [n * HPAD + q * 4] = bi;
    }
    __syncthreads();

    int og = tid & 7;
    int nb = tid >> 3;
    int nA = nb * 2, nB = nA + 1;

    float acc1[2][OPT], acc2[2][OPT];
    #pragma unroll
    for (int i = 0; i < OPT; i++) {
        int o = og + 8 * i;
        acc1[0][i] = b1[o]; acc1[1][i] = b1[o];
        acc2[0][i] = b2[o]; acc2[1][i] = b2[o];
    }

    #pragma unroll 4
    for (int d4 = 0; d4 < 16; d4++) {
        f16x4 sA = *(const f16x4*)&s_sum[nA * HPAD + d4 * 4];
        f16x4 bA = *(const f16x4*)&s_bi [nA * HPAD + d4 * 4];
        f16x4 sB = *(const f16x4*)&s_sum[nB * HPAD + d4 * 4];
        f16x4 bB = *(const f16x4*)&s_bi [nB * HPAD + d4 * 4];
        f16x2 sA0 = {sA[0], sA[1]}, sA1 = {sA[2], sA[3]};
        f16x2 bA0 = {bA[0], bA[1]}, bA1 = {bA[2], bA[3]};
        f16x2 sB0 = {sB[0], sB[1]}, sB1 = {sB[2], sB[3]};
        f16x2 bB0 = {bB[0], bB[1]}, bB1 = {bB[2], bB[3]};
        #pragma unroll
        for (int i = 0; i < OPT; i++) {
            int o = og + 8 * i;
            f16x4 w1 = *(const f16x4*)&W1h[o * HPAD + d4 * 4];
            f16x4 w2 = *(const f16x4*)&W2h[o * HPAD + d4 * 4];
            f16x2 w10 = {w1[0], w1[1]}, w11 = {w1[2], w1[3]};
            f16x2 w20 = {w2[0], w2[1]}, w21 = {w2[2], w2[3]};
            acc1[0][i] = FDOT2(sA1, w11, FDOT2(sA0, w10, acc1[0][i]));
            acc1[1][i] = FDOT2(sB1, w11, FDOT2(sB0, w10, acc1[1][i]));
            acc2[0][i] = FDOT2(bA1, w21, FDOT2(bA0, w20, acc2[0][i]));
            acc2[1][i] = FDOT2(bB1, w21, FDOT2(bB0, w20, acc2[1][i]));
        }
    }

    float eo[2][OPT];
    float ss0 = 0.0f, ss1 = 0.0f;
    #pragma unroll
    for (int i = 0; i < OPT; i++) {
        float a = acc1[0][i]; a = a > 0.0f ? a : 0.01f * a;
        float c = acc2[0][i]; c = c > 0.0f ? c : 0.01f * c;
        eo[0][i] = a + c; ss0 += eo[0][i] * eo[0][i];
        a = acc1[1][i]; a = a > 0.0f ? a : 0.01f * a;
        c = acc2[1][i]; c = c > 0.0f ? c : 0.01f * c;
        eo[1][i] = a + c; ss1 += eo[1][i] * eo[1][i];
    }
    #pragma unroll
    for (int m = 1; m <= 4; m <<= 1) {
        ss0 += __shfl_xor(ss0, m);
        ss1 += __shfl_xor(ss1, m);
    }
    float inv0 = rsqrtf(fmaxf(ss0, 1e-24f));
    float inv1 = rsqrtf(fmaxf(ss1, 1e-24f));

    int liA = n0 + nA, liB = n0 + nB;
    int gnA = (liA < cntv) ? list[liA] : -1;
    int gnB = (liB < cntv) ? list[liB] : -1;
    #pragma unroll
    for (int i = 0; i < OPT; i++) {
        int o = og + 8 * i;
        if (gnA >= 0) {
            out_norm[(size_t)gnA * OSTR + o] = (f16)(eo[0][i] * inv0);
            if (WRITE_RAW) out_raw[(size_t)gnA * 64 + o] = (f16)eo[0][i];
        }
        if (gnB >= 0) {
            out_norm[(size_t)gnB * OSTR + o] = (f16)(eo[1][i] * inv1);
            if (WRITE_RAW) out_raw[(size_t)gnB * 64 + o] = (f16)eo[1][i];
        }
    }
}

// ---------------- Score GEMM: MFMA 16x16x32 f16, rows from e0c(64) + e12(96) ----------------
__global__ __launch_bounds__(256) void score_kernel(
    const f16* __restrict__ e0c, const f16* __restrict__ e12,
    const int* __restrict__ uids, const int* __restrict__ iids,
    float* __restrict__ out, int n_items)
{
    __shared__ f16 Us[64 * SRP];
    __shared__ f16 Vs[64 * SRP];
    int tid = threadIdx.x;
    int i0 = blockIdx.y * 64, j0 = blockIdx.x * 64;

    for (int t = tid; t < 64 * 20; t += 256) {
        int r = t / 20, c = t % 20;
        int uid = uids[i0 + r];
        int iid = iids[j0 + r];
        f16x8 u, v;
        if (c < 8) {
            u = *(const f16x8*)&e0c[(size_t)uid * 64 + c * 8];
            v = *(const f16x8*)&e0c[(size_t)iid * 64 + c * 8];
        } else {
            u = *(const f16x8*)&e12[(size_t)uid * 96 + (c - 8) * 8];
            v = *(const f16x8*)&e12[(size_t)iid * 96 + (c - 8) * 8];
        }
        *(f16x8*)&Us[r * SRP + c * 8] = u;
        *(f16x8*)&Vs[r * SRP + c * 8] = v;
    }
    __syncthreads();

    int w = tid >> 6, lane = tid & 63;
    int wr = (w >> 1) * 32, wc = (w & 1) * 32;
    int lr = lane & 15, lk = (lane >> 4) * 8;

    f32x4 acc00 = {0,0,0,0}, acc01 = {0,0,0,0}, acc10 = {0,0,0,0}, acc11 = {0,0,0,0};
    #pragma unroll
    for (int kc = 0; kc < 160; kc += 32) {
        f16x8 a0 = *(const f16x8*)&Us[(wr +      lr) * SRP + kc + lk];
        f16x8 a1 = *(const f16x8*)&Us[(wr + 16 + lr) * SRP + kc + lk];
        f16x8 b0 = *(const f16x8*)&Vs[(wc +      lr) * SRP + kc + lk];
        f16x8 b1 = *(const f16x8*)&Vs[(wc + 16 + lr) * SRP + kc + lk];
        acc00 = __builtin_amdgcn_mfma_f32_16x16x32_f16(a0, b0, acc00, 0, 0, 0);
        acc01 = __builtin_amdgcn_mfma_f32_16x16x32_f16(a0, b1, acc01, 0, 0, 0);
        acc10 = __builtin_amdgcn_mfma_f32_16x16x32_f16(a1, b0, acc10, 0, 0, 0);
        acc11 = __builtin_amdgcn_mfma_f32_16x16x32_f16(a1, b1, acc11, 0, 0, 0);
    }

    int orow = (lane >> 4) * 4, ocol = lane & 15;
    #pragma unroll
    for (int r = 0; r < 4; r++) {
        int iA = i0 + wr + orow + r;
        int iB = i0 + wr + 16 + orow + r;
        out[(size_t)iA * n_items + j0 + wc +      ocol] = acc00[r];
        out[(size_t)iA * n_items + j0 + wc + 16 + ocol] = acc01[r];
        out[(size_t)iB * n_items + j0 + wc +      ocol] = acc10[r];
        out[(size_t)iB * n_items + j0 + wc + 16 + ocol] = acc11[r];
    }
}

extern "C" void kernel_launch(void* const* d_in, const int* in_sizes, int n_in,
                              void* d_out, int out_size, void* d_ws, size_t ws_size,
                              hipStream_t stream) {
    const int*   user_ids = (const int*)  d_in[0];
    const int*   item_ids = (const int*)  d_in[1];
    const float* aux      = (const float*)d_in[2];
    const int*   A_rows   = (const int*)  d_in[3];
    const int*   A_cols   = (const int*)  d_in[4];
    const float* A_vals   = (const float*)d_in[5];
    const float* entity   = (const float*)d_in[6];
    const float* type_emb = (const float*)d_in[7];
    const float* W_aux    = (const float*)d_in[8];
    const float* b_aux    = (const float*)d_in[9];
    const float* W1_0     = (const float*)d_in[10];
    const float* b1_0     = (const float*)d_in[11];
    const float* W2_0     = (const float*)d_in[12];
    const float* b2_0     = (const float*)d_in[13];
    const float* W1_1     = (const float*)d_in[14];
    const float* b1_1     = (const float*)d_in[15];
    const float* W2_1     = (const float*)d_in[16];
    const float* b2_1     = (const float*)d_in[17];

    int E       = in_sizes[3];
    int n_users = in_sizes[0];
    int n_items = in_sizes[1];
    int ntiles  = (E + TILE_C - 1) / TILE_C;

    char* ws = (char*)d_ws;
    size_t off = 0;
    f16*   e0c    = (f16*)  (ws + off); off += (size_t)NN * 64 * 2;    // 12.8 MB
    f16*   e12    = (f16*)  (ws + off); off += (size_t)NN * 96 * 2;    // 19.2 MB
    f16*   e1raw  = (f16*)  (ws + off); off += (size_t)NN * 64 * 2;    // 12.8 MB
    f16*   side   = (f16*)  (ws + off); off += (size_t)NN * 64 * 2;    // 12.8 MB
    uint2* cv     = (uint2*)(ws + off); off += (size_t)E * 8;          // 12.8 MB
    unsigned char* ebit = (unsigned char*)(ws + off); off += (size_t)E; // 1.6 MB
    int*   locCnt = (int*)  (ws + off); off += (size_t)NBK * MAXT * 4; // 0.63 MB
    int*   gposM  = (int*)  (ws + off); off += (size_t)NBK * MAXT * 4; // 0.63 MB
    int*   rowptr = (int*)  (ws + off); off += (size_t)(NN + 1) * 4;
    int*   bstart = (int*)  (ws + off); off += (size_t)(NBK + 1) * 4;
    int*   L0     = (int*)  (ws + off); off += (size_t)NN * 4;
    int*   L1     = (int*)  (ws + off); off += (size_t)NN * 4;
    // contiguous zero-init region: bcnt | f0 | f1 | cnt0 | cnt1
    char*  zbase  = ws + off;
    int*   bcnt   = (int*)  (ws + off); off += (size_t)NBK * 4;
    int*   f0     = (int*)  (ws + off); off += (size_t)NN * 4;
    int*   f1     = (int*)  (ws + off); off += (size_t)NN * 4;
    int*   cnt0   = (int*)  (ws + off); off += 4;
    int*   cnt1   = (int*)  (ws + off); off += 4;
    size_t zbytes = (size_t)(NBK + 2 * NN + 2) * 4;

    hipMemsetAsync(zbase, 0, zbytes, stream);

    // ---- Demand cone (COO scan): L1 = ids, L0 = L1 ∪ cols(rows in L1) ----
    int nid = n_users + n_items;
    mark_ids<<<(nid + 255) / 256, 256, 0, stream>>>(user_ids, n_users,
                                                    item_ids, n_items, f0, f1);
    mark_edges<<<2048, 256, 0, stream>>>(A_rows, A_cols, E, f1, f0);
    compact_kernel<<<(NN + 255) / 256, 256, 0, stream>>>(f0, L0, cnt0);
    compact_kernel<<<(NN + 255) / 256, 256, 0, stream>>>(f1, L1, cnt1);

    // ---- CSR build over flagged rows only (single-pass scatter) ----
    bucket_hist<<<ntiles, 1024, 0, stream>>>(A_rows, E, f0, bcnt, ebit, locCnt);
    bucket_scan<<<1, 1024, 0, stream>>>(bcnt, bstart, rowptr);
    gpos_scan<<<(NBK + 3) / 4, 256, 0, stream>>>(bstart, locCnt, gposM, ntiles);
    bucket_scatter<<<ntiles, 1024, 0, stream>>>(A_rows, A_cols, A_vals, E, ebit,
                                                gposM, cv);
    bucket_sort<<<NBK, 256, 0, stream>>>(bstart, cv, rowptr);

    // ---- Stage A: e0c (all nodes) ----
    fuse_kernel<<<NN / 4, 256, 0, stream>>>(aux, entity, type_emb, W_aux, b_aux, e0c);

    int sgrid_rows = (NN + 3) / 4;
    int lgrid      = (NN + 63) / 64;

    // ---- Layer 0 over L0: norm -> e12[:,0:64], raw -> e1raw ----
    spmm_csr_list<64><<<sgrid_rows, 256, 0, stream>>>(rowptr, cv, e0c, side, L0, cnt0);
    layer_kernel<64, 64, 96, true><<<lgrid, 256, 0, stream>>>(e0c, side,
                                                              W1_0, b1_0, W2_0, b2_0,
                                                              e12, e1raw, L0, cnt0);

    // ---- Layer 1 over L1: norm -> e12[:,64:96] ----
    spmm_csr_list<64><<<sgrid_rows, 256, 0, stream>>>(rowptr, cv, e1raw, side, L1, cnt1);
    layer_kernel<32, 64, 96, false><<<lgrid, 256, 0, stream>>>(e1raw, side,
                                                               W1_1, b1_1, W2_1, b2_1,
                                                               e12 + 64, nullptr, L1, cnt1);

    // ---- Score (MFMA) ----
    dim3 sgrid(n_items / 64, n_users / 64);
    score_kernel<<<sgrid, 256, 0, stream>>>(e0c, e12, user_ids, item_ids,
                                            (float*)d_out, n_items);
}